// Round 10
// baseline (270.674 us; speedup 1.0000x reference)
//
#include <hip/hip_runtime.h>
#include <math.h>

// Problem constants (from reference setup_inputs)
constexpr int B_ = 8, N_ = 32768, CAT_ = 128, FEAT_ = 128, K_ = 64;
constexpr float DELTA_ = 0.5f;

typedef __bf16 bf16x8 __attribute__((ext_vector_type(8)));
typedef float f32x4 __attribute__((ext_vector_type(4)));
typedef float f32x16 __attribute__((ext_vector_type(16)));

constexpr int BLOCK = 1024;                      // 16 waves share one weight tile
constexpr int NPB   = 512;                       // n-rows per block (32 per wave)
constexpr int GEMM_BLOCKS = (B_ * N_) / NPB;     // 512

#define AS1 __attribute__((address_space(1)))
#define AS3 __attribute__((address_space(3)))

// ---------------------------------------------------------------------------
// prep: builds bf16 W^T [FEAT][CAT], XOR-swizzled within each row
// (wT_swz[f][c ^ ((f&7)<<3)] = w[c][f]) so a LINEAR global_load_lds copy
// yields a swizzled LDS image (G21). Also produces new_weight.
// grid = CAT_ blocks x FEAT_ threads.
// ---------------------------------------------------------------------------
__global__ void prep_kernel(const float* __restrict__ weight,
                            const int* __restrict__ keys,
                            const float* __restrict__ values,
                            float* __restrict__ outw,    // [CAT][FEAT]
                            __bf16* __restrict__ wTs)    // [FEAT][CAT] swizzled
{
    const int r = blockIdx.x;    // weight row (CAT index = c)
    const int t = threadIdx.x;   // FEAT index (f)
    float w = weight[r * FEAT_ + t];
    wTs[t * CAT_ + (r ^ ((t & 7) << 3))] = (__bf16)w;

    bool keyed = false;
    for (int i = 0; i < K_; ++i) keyed |= (keys[i] == r);
    if (!keyed) outw[r * FEAT_ + t] = w;

    if (r < K_ && t < 64) {
        const int key = keys[r];
        float a0 = DELTA_ * weight[key * FEAT_ + t]      + (1.0f - DELTA_) * values[r * FEAT_ + t];
        float a1 = DELTA_ * weight[key * FEAT_ + t + 64] + (1.0f - DELTA_) * values[r * FEAT_ + t + 64];
        float ss = a0 * a0 + a1 * a1;
        #pragma unroll
        for (int off = 32; off > 0; off >>= 1)
            ss += __shfl_down(ss, off, 64);
        float nrm = sqrtf(__shfl(ss, 0, 64));
        outw[key * FEAT_ + t]      = nrm;
        outw[key * FEAT_ + t + 64] = nrm;
    }
}

// ---------------------------------------------------------------------------
// gemm (32x32x16 MFMA, R8 structure, widened n-span per block):
//   out[b][f][n] = sum_c input[b][n][c] * w[c][f]
//  - 16 waves share ONE 32KB LDS weight tile (global_load_lds staged)
//  - input: direct f32x4 loads in the ck-loop (R9 proved LDS input staging
//    is not better; latency is not the binding constraint)
//  - NPB=512: each f-row written in 2KB contiguous chunks (vs 1KB at R8)
//    -> fewer strided DRAM row transitions on the write stream (2/3 of
//    HBM traffic). Wave tile unchanged (32n x 128f), VGPR unchanged.
//  - D layout (m74/m101): col=lane&31 -> n, row=(reg&3)+8*(reg>>2)+4*kg -> f
// ---------------------------------------------------------------------------
__global__ __launch_bounds__(BLOCK, 8) void gemm_kernel(
    const float* __restrict__ input,   // [B][N][CAT]
    const __bf16* __restrict__ wTs,    // [FEAT][CAT] bf16, swizzled
    float* __restrict__ out)           // [B][FEAT][N]
{
    __shared__ __bf16 wt[FEAT_ * CAT_];  // 32 KB, linear copy of wTs (pre-swizzled)

    const int tid  = threadIdx.x;
    const int wid  = tid >> 6;           // 0..15
    const int lane = tid & 63;

    // stage wT_swz -> LDS: 2 iters x 16 waves x (64 lanes x 16B) = 32 KB
    #pragma unroll
    for (int j = 0; j < 2; ++j) {
        int off = j * 16384 + wid * 1024;  // bytes; wave-uniform LDS base
        __builtin_amdgcn_global_load_lds(
            (const AS1 void*)((const char*)wTs + off + lane * 16),
            (AS3 void*)((char*)wt + off), 16, 0, 0);
    }

    const int nl = lane & 31;    // n within wave tile / f within mt tile
    const int kg = lane >> 5;    // 0..1, k-group of 8
    const int bid = blockIdx.x;
    const int b   = bid >> 6;    // 64 blocks per batch
    const int nb  = bid & 63;
    const int n0  = nb * NPB + wid * 32;  // this wave's n start (32 n per wave)

    f32x16 acc[4];
    #pragma unroll
    for (int i = 0; i < 4; ++i)
        acc[i] = (f32x16)0.0f;

    const float* inp = input + ((size_t)b * N_ + n0 + nl) * CAT_;

    __syncthreads();

    #pragma unroll
    for (int ck = 0; ck < 8; ++ck) {     // K-steps of 16
        const int c0 = ck * 16 + kg * 8;
        f32x4 v0 = *(const f32x4*)(inp + c0);
        f32x4 v1 = *(const f32x4*)(inp + c0 + 4);
        bf16x8 bfrag;
        #pragma unroll
        for (int e = 0; e < 4; ++e) {
            bfrag[e]     = (__bf16)v0[e];
            bfrag[e + 4] = (__bf16)v1[e];
        }
        #pragma unroll
        for (int mt = 0; mt < 4; ++mt) { // 4 f subtiles of 32
            const int f = mt * 32 + nl;
            bf16x8 af = *(const bf16x8*)&wt[f * CAT_ + (c0 ^ ((f & 7) << 3))];
            acc[mt] = __builtin_amdgcn_mfma_f32_32x32x16_bf16(af, bfrag, acc[mt], 0, 0, 0);
        }
    }

    // epilogue: full-128B-line stores
    float* outp = out + (size_t)b * FEAT_ * N_ + n0 + nl;
    #pragma unroll
    for (int mt = 0; mt < 4; ++mt) {
        #pragma unroll
        for (int r = 0; r < 16; ++r) {
            const int f = mt * 32 + (r & 3) + 8 * (r >> 2) + 4 * kg;
            __builtin_nontemporal_store(acc[mt][r], outp + (size_t)f * N_);
        }
    }
}

// ---------------------------------------------------------------------------
// Fallback (R1 kernel): single launch with per-block LDS staging, used only
// if the workspace is too small for wT_swz.
// ---------------------------------------------------------------------------
constexpr int LDSTR = 136;
constexpr int FB_BLOCKS = (B_ * N_) / 128;  // 2048

__global__ __launch_bounds__(256, 4) void ocm_fused(
    const float* __restrict__ input,
    const float* __restrict__ weight,
    const int* __restrict__ keys,
    const float* __restrict__ values,
    float* __restrict__ out)
{
    const int bid = blockIdx.x;
    const int tid = threadIdx.x;

    if (bid >= FB_BLOCKS) {
        float* outw = out + (size_t)B_ * FEAT_ * N_;
        const int r = bid - FB_BLOCKS;
        bool keyed = false;
        for (int i = 0; i < K_; ++i) keyed |= (keys[i] == r);
        if (!keyed && tid < FEAT_)
            outw[r * FEAT_ + tid] = weight[r * FEAT_ + tid];
        if (r < K_ && tid < 64) {
            const int key = keys[r];
            float a0 = DELTA_ * weight[key * FEAT_ + tid]      + (1.0f - DELTA_) * values[r * FEAT_ + tid];
            float a1 = DELTA_ * weight[key * FEAT_ + tid + 64] + (1.0f - DELTA_) * values[r * FEAT_ + tid + 64];
            float ss = a0 * a0 + a1 * a1;
            #pragma unroll
            for (int off = 32; off > 0; off >>= 1)
                ss += __shfl_down(ss, off, 64);
            float nrm = sqrtf(__shfl(ss, 0, 64));
            outw[key * FEAT_ + tid]      = nrm;
            outw[key * FEAT_ + tid + 64] = nrm;
        }
        return;
    }

    __shared__ __bf16 wt[FEAT_ * LDSTR];
    #pragma unroll
    for (int j = 0; j < (CAT_ * FEAT_) / 256; ++j) {
        int i = tid + j * 256;
        int c = i >> 7;
        int f = i & (FEAT_ - 1);
        wt[f * LDSTR + c] = (__bf16)weight[i];
    }
    __syncthreads();

    const int wid  = tid >> 6;
    const int lane = tid & 63;
    const int qlo  = lane & 15;
    const int qhi  = lane >> 4;
    const int b    = bid >> 8;
    const int nb   = bid & 255;
    const int n0   = nb * 128 + wid * 32;

    f32x4 acc[8][2];
    #pragma unroll
    for (int i = 0; i < 8; ++i)
        #pragma unroll
        for (int j = 0; j < 2; ++j)
            acc[i][j] = (f32x4)0.0f;

    const float* in_base = input + ((size_t)b * N_ + n0) * CAT_;

    #pragma unroll
    for (int ck = 0; ck < 4; ++ck) {
        bf16x8 bfrag[2];
        #pragma unroll
        for (int nt = 0; nt < 2; ++nt) {
            const float* p = in_base + (size_t)(nt * 16 + qlo) * CAT_ + ck * 32 + qhi * 8;
            f32x4 v0 = *(const f32x4*)p;
            f32x4 v1 = *(const f32x4*)(p + 4);
            bf16x8 t;
            t[0] = (__bf16)v0[0]; t[1] = (__bf16)v0[1]; t[2] = (__bf16)v0[2]; t[3] = (__bf16)v0[3];
            t[4] = (__bf16)v1[0]; t[5] = (__bf16)v1[1]; t[6] = (__bf16)v1[2]; t[7] = (__bf16)v1[3];
            bfrag[nt] = t;
        }
        #pragma unroll
        for (int mt = 0; mt < 8; ++mt) {
            bf16x8 afrag = *(const bf16x8*)&wt[(mt * 16 + qlo) * LDSTR + ck * 32 + qhi * 8];
            acc[mt][0] = __builtin_amdgcn_mfma_f32_16x16x32_bf16(afrag, bfrag[0], acc[mt][0], 0, 0, 0);
            acc[mt][1] = __builtin_amdgcn_mfma_f32_16x16x32_bf16(afrag, bfrag[1], acc[mt][1], 0, 0, 0);
        }
    }

    float* outp = out + (size_t)b * FEAT_ * N_ + n0;
    #pragma unroll
    for (int mt = 0; mt < 8; ++mt) {
        #pragma unroll
        for (int nt = 0; nt < 2; ++nt) {
            #pragma unroll
            for (int r = 0; r < 4; ++r) {
                int f = mt * 16 + qhi * 4 + r;
                outp[(size_t)f * N_ + nt * 16 + qlo] = acc[mt][nt][r];
            }
        }
    }
}

extern "C" void kernel_launch(void* const* d_in, const int* in_sizes, int n_in,
                              void* d_out, int out_size, void* d_ws, size_t ws_size,
                              hipStream_t stream) {
    const float* input  = (const float*)d_in[0];
    const float* weight = (const float*)d_in[1];
    const int*   keys   = (const int*)d_in[2];
    const float* values = (const float*)d_in[3];
    float* out = (float*)d_out;

    if (ws_size >= (size_t)CAT_ * FEAT_ * sizeof(__bf16)) {
        __bf16* wTs = (__bf16*)d_ws;
        float* outw = out + (size_t)B_ * FEAT_ * N_;
        prep_kernel<<<CAT_, FEAT_, 0, stream>>>(weight, keys, values, outw, wTs);
        gemm_kernel<<<GEMM_BLOCKS, BLOCK, 0, stream>>>(input, wTs, out);
    } else {
        ocm_fused<<<FB_BLOCKS + CAT_, 256, 0, stream>>>(input, weight, keys, values, out);
    }
}

// Round 11
// 52.818 us; speedup vs baseline: 5.1247x; 5.1247x over previous
//
#include <hip/hip_runtime.h>
#include <math.h>

// Problem constants (from reference setup_inputs)
constexpr int B_ = 8, N_ = 32768, CAT_ = 128, FEAT_ = 128, K_ = 64;
constexpr float DELTA_ = 0.5f;

typedef __bf16 bf16x8 __attribute__((ext_vector_type(8)));
typedef float f32x4 __attribute__((ext_vector_type(4)));
typedef float f32x16 __attribute__((ext_vector_type(16)));

constexpr int BLOCK = 1024;                      // 16 waves share one weight tile
constexpr int NPB   = 512;                       // n-rows per block (32 per wave)
constexpr int GEMM_BLOCKS = (B_ * N_) / NPB;     // 512

#define AS1 __attribute__((address_space(1)))
#define AS3 __attribute__((address_space(3)))

// ---------------------------------------------------------------------------
// prep: builds bf16 W^T [FEAT][CAT], XOR-swizzled within each row
// (wT_swz[f][c ^ ((f&7)<<3)] = w[c][f]) so a LINEAR global_load_lds copy
// yields a swizzled LDS image (G21). Also produces new_weight.
// grid = CAT_ blocks x FEAT_ threads.
// ---------------------------------------------------------------------------
__global__ void prep_kernel(const float* __restrict__ weight,
                            const int* __restrict__ keys,
                            const float* __restrict__ values,
                            float* __restrict__ outw,    // [CAT][FEAT]
                            __bf16* __restrict__ wTs)    // [FEAT][CAT] swizzled
{
    const int r = blockIdx.x;    // weight row (CAT index = c)
    const int t = threadIdx.x;   // FEAT index (f)
    float w = weight[r * FEAT_ + t];
    wTs[t * CAT_ + (r ^ ((t & 7) << 3))] = (__bf16)w;

    bool keyed = false;
    for (int i = 0; i < K_; ++i) keyed |= (keys[i] == r);
    if (!keyed) outw[r * FEAT_ + t] = w;

    if (r < K_ && t < 64) {
        const int key = keys[r];
        float a0 = DELTA_ * weight[key * FEAT_ + t]      + (1.0f - DELTA_) * values[r * FEAT_ + t];
        float a1 = DELTA_ * weight[key * FEAT_ + t + 64] + (1.0f - DELTA_) * values[r * FEAT_ + t + 64];
        float ss = a0 * a0 + a1 * a1;
        #pragma unroll
        for (int off = 32; off > 0; off >>= 1)
            ss += __shfl_down(ss, off, 64);
        float nrm = sqrtf(__shfl(ss, 0, 64));
        outw[key * FEAT_ + t]      = nrm;
        outw[key * FEAT_ + t + 64] = nrm;
    }
}

// ---------------------------------------------------------------------------
// gemm (32x32x16 MFMA, R8 structure, widened n-span per block):
//   out[b][f][n] = sum_c input[b][n][c] * w[c][f]
//  - 16 waves share ONE 32KB LDS weight tile (global_load_lds staged)
//  - input: direct f32x4 loads in the ck-loop
//  - NPB=512: each f-row written in 2KB contiguous chunks (vs 1KB at R8)
//  - __launch_bounds__(1024, 4): min-waves arg is PER SIMD; R10's value 8
//    capped VGPRs at 32 and spilled the whole 64-reg accumulator to
//    scratch (WRITE 720MB, 270us). 4 -> 128-VGPR cap, acc fits.
//  - D layout (m74/m101): col=lane&31 -> n, row=(reg&3)+8*(reg>>2)+4*kg -> f
// ---------------------------------------------------------------------------
__global__ __launch_bounds__(BLOCK, 4) void gemm_kernel(
    const float* __restrict__ input,   // [B][N][CAT]
    const __bf16* __restrict__ wTs,    // [FEAT][CAT] bf16, swizzled
    float* __restrict__ out)           // [B][FEAT][N]
{
    __shared__ __bf16 wt[FEAT_ * CAT_];  // 32 KB, linear copy of wTs (pre-swizzled)

    const int tid  = threadIdx.x;
    const int wid  = tid >> 6;           // 0..15
    const int lane = tid & 63;

    // stage wT_swz -> LDS: 2 iters x 16 waves x (64 lanes x 16B) = 32 KB
    #pragma unroll
    for (int j = 0; j < 2; ++j) {
        int off = j * 16384 + wid * 1024;  // bytes; wave-uniform LDS base
        __builtin_amdgcn_global_load_lds(
            (const AS1 void*)((const char*)wTs + off + lane * 16),
            (AS3 void*)((char*)wt + off), 16, 0, 0);
    }

    const int nl = lane & 31;    // n within wave tile / f within mt tile
    const int kg = lane >> 5;    // 0..1, k-group of 8
    const int bid = blockIdx.x;
    const int b   = bid >> 6;    // 64 blocks per batch
    const int nb  = bid & 63;
    const int n0  = nb * NPB + wid * 32;  // this wave's n start (32 n per wave)

    f32x16 acc[4];
    #pragma unroll
    for (int i = 0; i < 4; ++i)
        acc[i] = (f32x16)0.0f;

    const float* inp = input + ((size_t)b * N_ + n0 + nl) * CAT_;

    __syncthreads();

    #pragma unroll
    for (int ck = 0; ck < 8; ++ck) {     // K-steps of 16
        const int c0 = ck * 16 + kg * 8;
        f32x4 v0 = *(const f32x4*)(inp + c0);
        f32x4 v1 = *(const f32x4*)(inp + c0 + 4);
        bf16x8 bfrag;
        #pragma unroll
        for (int e = 0; e < 4; ++e) {
            bfrag[e]     = (__bf16)v0[e];
            bfrag[e + 4] = (__bf16)v1[e];
        }
        #pragma unroll
        for (int mt = 0; mt < 4; ++mt) { // 4 f subtiles of 32
            const int f = mt * 32 + nl;
            bf16x8 af = *(const bf16x8*)&wt[f * CAT_ + (c0 ^ ((f & 7) << 3))];
            acc[mt] = __builtin_amdgcn_mfma_f32_32x32x16_bf16(af, bfrag, acc[mt], 0, 0, 0);
        }
    }

    // epilogue: full-128B-line stores
    float* outp = out + (size_t)b * FEAT_ * N_ + n0 + nl;
    #pragma unroll
    for (int mt = 0; mt < 4; ++mt) {
        #pragma unroll
        for (int r = 0; r < 16; ++r) {
            const int f = mt * 32 + (r & 3) + 8 * (r >> 2) + 4 * kg;
            __builtin_nontemporal_store(acc[mt][r], outp + (size_t)f * N_);
        }
    }
}

// ---------------------------------------------------------------------------
// Fallback (R1 kernel): single launch with per-block LDS staging, used only
// if the workspace is too small for wT_swz.
// ---------------------------------------------------------------------------
constexpr int LDSTR = 136;
constexpr int FB_BLOCKS = (B_ * N_) / 128;  // 2048

__global__ __launch_bounds__(256, 4) void ocm_fused(
    const float* __restrict__ input,
    const float* __restrict__ weight,
    const int* __restrict__ keys,
    const float* __restrict__ values,
    float* __restrict__ out)
{
    const int bid = blockIdx.x;
    const int tid = threadIdx.x;

    if (bid >= FB_BLOCKS) {
        float* outw = out + (size_t)B_ * FEAT_ * N_;
        const int r = bid - FB_BLOCKS;
        bool keyed = false;
        for (int i = 0; i < K_; ++i) keyed |= (keys[i] == r);
        if (!keyed && tid < FEAT_)
            outw[r * FEAT_ + tid] = weight[r * FEAT_ + tid];
        if (r < K_ && tid < 64) {
            const int key = keys[r];
            float a0 = DELTA_ * weight[key * FEAT_ + tid]      + (1.0f - DELTA_) * values[r * FEAT_ + tid];
            float a1 = DELTA_ * weight[key * FEAT_ + tid + 64] + (1.0f - DELTA_) * values[r * FEAT_ + tid + 64];
            float ss = a0 * a0 + a1 * a1;
            #pragma unroll
            for (int off = 32; off > 0; off >>= 1)
                ss += __shfl_down(ss, off, 64);
            float nrm = sqrtf(__shfl(ss, 0, 64));
            outw[key * FEAT_ + tid]      = nrm;
            outw[key * FEAT_ + tid + 64] = nrm;
        }
        return;
    }

    __shared__ __bf16 wt[FEAT_ * LDSTR];
    #pragma unroll
    for (int j = 0; j < (CAT_ * FEAT_) / 256; ++j) {
        int i = tid + j * 256;
        int c = i >> 7;
        int f = i & (FEAT_ - 1);
        wt[f * LDSTR + c] = (__bf16)weight[i];
    }
    __syncthreads();

    const int wid  = tid >> 6;
    const int lane = tid & 63;
    const int qlo  = lane & 15;
    const int qhi  = lane >> 4;
    const int b    = bid >> 8;
    const int nb   = bid & 255;
    const int n0   = nb * 128 + wid * 32;

    f32x4 acc[8][2];
    #pragma unroll
    for (int i = 0; i < 8; ++i)
        #pragma unroll
        for (int j = 0; j < 2; ++j)
            acc[i][j] = (f32x4)0.0f;

    const float* in_base = input + ((size_t)b * N_ + n0) * CAT_;

    #pragma unroll
    for (int ck = 0; ck < 4; ++ck) {
        bf16x8 bfrag[2];
        #pragma unroll
        for (int nt = 0; nt < 2; ++nt) {
            const float* p = in_base + (size_t)(nt * 16 + qlo) * CAT_ + ck * 32 + qhi * 8;
            f32x4 v0 = *(const f32x4*)p;
            f32x4 v1 = *(const f32x4*)(p + 4);
            bf16x8 t;
            t[0] = (__bf16)v0[0]; t[1] = (__bf16)v0[1]; t[2] = (__bf16)v0[2]; t[3] = (__bf16)v0[3];
            t[4] = (__bf16)v1[0]; t[5] = (__bf16)v1[1]; t[6] = (__bf16)v1[2]; t[7] = (__bf16)v1[3];
            bfrag[nt] = t;
        }
        #pragma unroll
        for (int mt = 0; mt < 8; ++mt) {
            bf16x8 afrag = *(const bf16x8*)&wt[(mt * 16 + qlo) * LDSTR + ck * 32 + qhi * 8];
            acc[mt][0] = __builtin_amdgcn_mfma_f32_16x16x32_bf16(afrag, bfrag[0], acc[mt][0], 0, 0, 0);
            acc[mt][1] = __builtin_amdgcn_mfma_f32_16x16x32_bf16(afrag, bfrag[1], acc[mt][1], 0, 0, 0);
        }
    }

    float* outp = out + (size_t)b * FEAT_ * N_ + n0;
    #pragma unroll
    for (int mt = 0; mt < 8; ++mt) {
        #pragma unroll
        for (int nt = 0; nt < 2; ++nt) {
            #pragma unroll
            for (int r = 0; r < 4; ++r) {
                int f = mt * 16 + qhi * 4 + r;
                outp[(size_t)f * N_ + nt * 16 + qlo] = acc[mt][nt][r];
            }
        }
    }
}

extern "C" void kernel_launch(void* const* d_in, const int* in_sizes, int n_in,
                              void* d_out, int out_size, void* d_ws, size_t ws_size,
                              hipStream_t stream) {
    const float* input  = (const float*)d_in[0];
    const float* weight = (const float*)d_in[1];
    const int*   keys   = (const int*)d_in[2];
    const float* values = (const float*)d_in[3];
    float* out = (float*)d_out;

    if (ws_size >= (size_t)CAT_ * FEAT_ * sizeof(__bf16)) {
        __bf16* wTs = (__bf16*)d_ws;
        float* outw = out + (size_t)B_ * FEAT_ * N_;
        prep_kernel<<<CAT_, FEAT_, 0, stream>>>(weight, keys, values, outw, wTs);
        gemm_kernel<<<GEMM_BLOCKS, BLOCK, 0, stream>>>(input, wTs, out);
    } else {
        ocm_fused<<<FB_BLOCKS + CAT_, 256, 0, stream>>>(input, weight, keys, values, out);
    }
}